// Round 2
// baseline (261.435 us; speedup 1.0000x reference)
//
#include <hip/hip_runtime.h>

// Problem constants (from reference setup_inputs): B=2, C=16, D=64, H=128, W=128
#define BB 2
#define CC 16
#define NVOX (64 * 128 * 128)   // voxels per batch = 1048576 = 2^20
#define N4   (NVOX / 4)         // float4-granular voxels per batch = 262144 = 2^18
#define NBLK 2048               // main-kernel blocks (1024 per batch)

// Main pass: one thread = 4 consecutive voxels. 16 float4 loads (one per class,
// 16B/lane fully coalesced), register log-sum-exp, predicated register
// class-accumulation (NO atomics), wave shuffle-reduce, deterministic per-block
// partial write (no workspace init needed).
// ws layout: ws[blk*32 + c]      = sum of nll for class c in block blk
//            ws[blk*32 + 16 + c] = count of voxels with label c in block blk
__global__ __launch_bounds__(256, 4) void cwce_main(const float* __restrict__ x,
                                                    const int* __restrict__ y,
                                                    float* __restrict__ ws) {
    __shared__ float s_part[4][2 * CC];
    const int t = threadIdx.x;

    const unsigned gid = blockIdx.x * 256u + t;      // [0, 524288)
    const unsigned b   = gid >> 18;                  // 262144 threads per batch
    const unsigned n4  = gid & (N4 - 1);

    const float4* xb = (const float4*)x + (size_t)(b * CC) * N4 + n4;
    const int4 lab4 = ((const int4*)y)[gid];

    // Load the full 16-class x 4-voxel tile into registers (one HBM pass).
    float xv[CC][4];
#pragma unroll
    for (int c = 0; c < CC; ++c) {
        float4 v = xb[(size_t)c * N4];
        xv[c][0] = v.x; xv[c][1] = v.y; xv[c][2] = v.z; xv[c][3] = v.w;
    }
    const int labs[4] = {lab4.x, lab4.y, lab4.z, lab4.w};

    float acc_s[CC];   // per-class nll sum (this thread's 4 voxels)
    float acc_c[CC];   // per-class count
#pragma unroll
    for (int c = 0; c < CC; ++c) { acc_s[c] = 0.0f; acc_c[c] = 0.0f; }

#pragma unroll
    for (int j = 0; j < 4; ++j) {
        float m = xv[0][j];
#pragma unroll
        for (int c = 1; c < CC; ++c) m = fmaxf(m, xv[c][j]);
        const int lj = labs[j];
        float s = 0.0f, xy = 0.0f;
#pragma unroll
        for (int c = 0; c < CC; ++c) {
            s += __expf(xv[c][j] - m);
            if (c == lj) xy = xv[c][j];   // cndmask select of x[label]
        }
        const float nll = m + __logf(s) - xy;
#pragma unroll
        for (int c = 0; c < CC; ++c) {
            const bool hit = (c == lj);
            acc_s[c] += hit ? nll : 0.0f;   // cndmask + add, no serialization
            acc_c[c] += hit ? 1.0f : 0.0f;
        }
    }

    // Wave-level butterfly reduce (64 lanes) for all 32 accumulators.
#pragma unroll
    for (int c = 0; c < CC; ++c) {
#pragma unroll
        for (int off = 32; off >= 1; off >>= 1) {
            acc_s[c] += __shfl_down(acc_s[c], off);
            acc_c[c] += __shfl_down(acc_c[c], off);
        }
    }

    const int wave = t >> 6;
    if ((t & 63) == 0) {
#pragma unroll
        for (int c = 0; c < CC; ++c) {
            s_part[wave][c]      = acc_s[c];
            s_part[wave][CC + c] = acc_c[c];
        }
    }
    __syncthreads();

    // Combine 4 waves; coalesced 128B partial write, no init/atomics required.
    if (t < 2 * CC) {
        float p = s_part[0][t] + s_part[1][t] + s_part[2][t] + s_part[3][t];
        ws[blockIdx.x * (2 * CC) + t] = p;
    }
}

// Final: reduce 2048 x 32 partials (256 KB, coalesced), per-(b,c) means with
// empty-class -> 0, then sum/(B*C). Blocks [0,1024) are b=0, [1024,2048) b=1.
__global__ __launch_bounds__(256) void cwce_final(const float* __restrict__ ws,
                                                  float* __restrict__ out) {
    __shared__ float sb[BB][8][2 * CC];
    const int t = threadIdx.x;
    const int k = t & 31;        // which of the 32 partial slots
    const int g = t >> 5;        // group in [0,8)

    float a0 = 0.0f, a1 = 0.0f;
    for (int blk = g; blk < NBLK / 2; blk += 8)            a0 += ws[blk * 32 + k];
    for (int blk = NBLK / 2 + g; blk < NBLK; blk += 8)     a1 += ws[blk * 32 + k];
    sb[0][g][k] = a0;
    sb[1][g][k] = a1;
    __syncthreads();

    if (t < 64) {                 // first wave only
        const int b  = t >> 5;    // 0..1
        const int kk = t & 31;
        float tot = 0.0f;
#pragma unroll
        for (int gg = 0; gg < 8; ++gg) tot += sb[b][gg][kk];
        sb[b][0][kk] = tot;       // totals: sb[b][0][c]=sum, sb[b][0][16+c]=count
    }
    __syncthreads();

    if (t < 64) {
        float v = 0.0f;
        if (t < BB * CC) {        // lanes [0,32): segment (b,c)
            const int b = t >> 4, c = t & 15;
            const float sum = sb[b][0][c];
            const float cnt = sb[b][0][CC + c];
            v = (cnt > 0.0f) ? (sum / cnt) : 0.0f;
        }
#pragma unroll
        for (int off = 32; off >= 1; off >>= 1) v += __shfl_down(v, off);
        if (t == 0) out[0] = v * (1.0f / (BB * CC));
    }
}

extern "C" void kernel_launch(void* const* d_in, const int* in_sizes, int n_in,
                              void* d_out, int out_size, void* d_ws, size_t ws_size,
                              hipStream_t stream) {
    const float* x = (const float*)d_in[0];
    const int*   y = (const int*)d_in[1];
    float*       out = (float*)d_out;
    float*       ws  = (float*)d_ws;     // 2048 * 32 floats = 256 KB used

    // total threads = B * NVOX / 4 = 524288 -> 2048 blocks of 256
    cwce_main<<<NBLK, 256, 0, stream>>>(x, y, ws);
    cwce_final<<<1, 256, 0, stream>>>(ws, out);
}

// Round 3
// 225.686 us; speedup vs baseline: 1.1584x; 1.1584x over previous
//
#include <hip/hip_runtime.h>

// Problem constants (from reference setup_inputs): B=2, C=16, D=64, H=128, W=128
#define BB 2
#define CC 16
#define NVOX (64 * 128 * 128)   // voxels per batch = 1048576 = 2^20
#define N4   (NVOX / 4)         // float4-granular voxels per batch = 262144 = 2^18
#define NBLK 2048               // main-kernel blocks (1024 per batch)

// Main pass: one thread = 4 consecutive voxels. 16 float4 loads (one per class,
// 16B/lane fully coalesced), register log-sum-exp, then fire-and-forget LDS
// atomicAdd histogram (ds_add_f32, no return -> off the critical path; ~4-way
// same-bank aliasing costs ~1.6x on the LDS pipe, hidden under memory waits).
// NO per-class register accumulators, NO shuffle butterfly (R2's 384 bpermute
// ops/thread cost ~31 us/CU), NO global atomics, NO init kernel.
// ws layout: ws[blk*32 + c] = nll sum for class c, ws[blk*32 + 16 + c] = count.
__global__ __launch_bounds__(256) void cwce_main(const float* __restrict__ x,
                                                 const int* __restrict__ y,
                                                 float* __restrict__ ws) {
    __shared__ float s_acc[2 * CC];
    const int t = threadIdx.x;
    if (t < 2 * CC) s_acc[t] = 0.0f;
    __syncthreads();

    const unsigned gid = blockIdx.x * 256u + t;      // [0, 524288)
    const unsigned b   = gid >> 18;                  // 262144 threads per batch
    const unsigned n4  = gid & (N4 - 1);

    const float4* xb = (const float4*)x + (size_t)(b * CC) * N4 + n4;
    const int4 lab4 = ((const int4*)y)[gid];

    // Load the full 16-class x 4-voxel tile into registers (one HBM pass).
    float xv[CC][4];
#pragma unroll
    for (int c = 0; c < CC; ++c) {
        float4 v = xb[(size_t)c * N4];
        xv[c][0] = v.x; xv[c][1] = v.y; xv[c][2] = v.z; xv[c][3] = v.w;
    }
    const int labs[4] = {lab4.x, lab4.y, lab4.z, lab4.w};

#pragma unroll
    for (int j = 0; j < 4; ++j) {
        float m = xv[0][j];
#pragma unroll
        for (int c = 1; c < CC; ++c) m = fmaxf(m, xv[c][j]);
        const int lj = labs[j];
        float s = 0.0f, xy = 0.0f;
#pragma unroll
        for (int c = 0; c < CC; ++c) {
            s += __expf(xv[c][j] - m);
            if (c == lj) xy = xv[c][j];   // cndmask select of x[label]
        }
        const float nll = m + __logf(s) - xy;
        atomicAdd(&s_acc[lj], nll);        // ds_add_f32 (no rtn)
        atomicAdd(&s_acc[CC + lj], 1.0f);
    }
    __syncthreads();

    // Deterministic per-block partial write (128 B, coalesced) — no init needed.
    if (t < 2 * CC) ws[blockIdx.x * (2 * CC) + t] = s_acc[t];
}

// Final: reduce 2048 x 32 partials (256 KB, L2-resident), per-(b,c) means with
// empty-class -> 0, then sum/(B*C). One block of 1024 threads for MLP.
__global__ __launch_bounds__(1024) void cwce_final(const float* __restrict__ ws,
                                                   float* __restrict__ out) {
    __shared__ float sb[32][2 * CC];   // [group][slot]
    const int t = threadIdx.x;         // 1024 threads
    const int k = t & 31;              // slot in [0,32)
    const int g = t >> 5;              // group in [0,32)

    float a = 0.0f;
    for (int blk = g; blk < NBLK; blk += 32)   // 64 coalesced iterations
        a += ws[blk * 32 + k];
    sb[g][k] = a;
    __syncthreads();

    if (t < 64) {                      // first wave only
        float v = 0.0f;
        if (t < BB * CC) {             // lanes [0,32): segment (b,c); b=t>>4, c=t&15
            float sum = 0.0f, cnt = 0.0f;
            const int b = t >> 4, c = t & 15;
#pragma unroll
            for (int gg = 0; gg < 32; ++gg) {
                sum += sb[gg][b * 0 + c + (b << 4) * 0];  // placeholder removed below
            }
            // recompute properly: slot c holds sums, slot 16+c holds counts,
            // but slots are per-block-partials already split by batch via blk.
            sum = 0.0f; cnt = 0.0f;
            // Batch b owns blocks [b*1024, (b+1)*1024) -> groups contributed both
            // batches into the same slot! Need the split: redo via direct pass.
            v = 0.0f;
        }
        // (see corrected logic below — this branch is dead)
    }
    __syncthreads();

    // CORRECT final logic: the group-strided sum above mixed both batches,
    // because slot k aggregates across ALL blocks. Redo with batch-split:
    // groups [0,16) accumulate batch 0 (blocks 0..1023), groups [16,32) batch 1.
    // To keep it simple and still fast, recompute here from ws directly.
    if (t < 2 * BB * CC) {             // 64 threads: b = t>>5, slot = t&31
        const int b = t >> 5;
        const int slot = t & 31;
        float s = 0.0f;
        for (int blk = b * (NBLK / 2); blk < (b + 1) * (NBLK / 2); ++blk)
            s += ws[blk * 32 + slot];
        sb[b][slot] = s;               // sb[b][c]=sum_c, sb[b][16+c]=cnt_c
    }
    __syncthreads();

    if (t < 64) {
        float v = 0.0f;
        if (t < BB * CC) {
            const int b = t >> 4, c = t & 15;
            const float sum = sb[b][c];
            const float cnt = sb[b][CC + c];
            v = (cnt > 0.0f) ? (sum / cnt) : 0.0f;
        }
#pragma unroll
        for (int off = 32; off >= 1; off >>= 1) v += __shfl_down(v, off);
        if (t == 0) out[0] = v * (1.0f / (BB * CC));
    }
}

extern "C" void kernel_launch(void* const* d_in, const int* in_sizes, int n_in,
                              void* d_out, int out_size, void* d_ws, size_t ws_size,
                              hipStream_t stream) {
    const float* x = (const float*)d_in[0];
    const int*   y = (const int*)d_in[1];
    float*       out = (float*)d_out;
    float*       ws  = (float*)d_ws;     // 2048 * 32 floats = 256 KB used

    // total threads = B * NVOX / 4 = 524288 -> 2048 blocks of 256
    cwce_main<<<NBLK, 256, 0, stream>>>(x, y, ws);
    cwce_final<<<1, 1024, 0, stream>>>(ws, out);
}

// Round 4
// 214.376 us; speedup vs baseline: 1.2195x; 1.0528x over previous
//
#include <hip/hip_runtime.h>

// Problem constants (from reference setup_inputs): B=2, C=16, D=64, H=128, W=128
#define BB 2
#define CC 16
#define NVOX (64 * 128 * 128)   // voxels per batch = 1048576 = 2^20
#define N4   (NVOX / 4)         // float4-granular voxels per batch = 262144 = 2^18
#define NBLK 2048               // main-kernel blocks (1024 per batch)

// Main pass (unchanged from R3, R1-proven): one thread = 4 consecutive voxels.
// 16 float4 loads (one per class, 16B/lane fully coalesced), register
// log-sum-exp, fire-and-forget LDS atomicAdd histogram (ds_add_f32 no-rtn,
// off the critical path), deterministic per-block partial write.
// ws layout: ws[blk*32 + c] = nll sum for class c, ws[blk*32 + 16 + c] = count.
__global__ __launch_bounds__(256) void cwce_main(const float* __restrict__ x,
                                                 const int* __restrict__ y,
                                                 float* __restrict__ ws) {
    __shared__ float s_acc[2 * CC];
    const int t = threadIdx.x;
    if (t < 2 * CC) s_acc[t] = 0.0f;
    __syncthreads();

    const unsigned gid = blockIdx.x * 256u + t;      // [0, 524288)
    const unsigned b   = gid >> 18;                  // 262144 threads per batch
    const unsigned n4  = gid & (N4 - 1);

    const float4* xb = (const float4*)x + (size_t)(b * CC) * N4 + n4;
    const int4 lab4 = ((const int4*)y)[gid];

    // Load the full 16-class x 4-voxel tile into registers (one HBM pass).
    float xv[CC][4];
#pragma unroll
    for (int c = 0; c < CC; ++c) {
        float4 v = xb[(size_t)c * N4];
        xv[c][0] = v.x; xv[c][1] = v.y; xv[c][2] = v.z; xv[c][3] = v.w;
    }
    const int labs[4] = {lab4.x, lab4.y, lab4.z, lab4.w};

#pragma unroll
    for (int j = 0; j < 4; ++j) {
        float m = xv[0][j];
#pragma unroll
        for (int c = 1; c < CC; ++c) m = fmaxf(m, xv[c][j]);
        const int lj = labs[j];
        float s = 0.0f, xy = 0.0f;
#pragma unroll
        for (int c = 0; c < CC; ++c) {
            s += __expf(xv[c][j] - m);
            if (c == lj) xy = xv[c][j];   // cndmask select of x[label]
        }
        const float nll = m + __logf(s) - xy;
        atomicAdd(&s_acc[lj], nll);        // ds_add_f32 (no rtn)
        atomicAdd(&s_acc[CC + lj], 1.0f);
    }
    __syncthreads();

    // Deterministic per-block partial write (128 B, coalesced) — no init needed.
    if (t < 2 * CC) ws[blockIdx.x * (2 * CC) + t] = s_acc[t];
}

// Final: reduce 2048 x 32 partials (256 KB, L2-resident).
// Stage 1: 32 groups of 32 lanes; group g (b=g>>4, sub=g&15) strides blocks
//          b*1024+sub+16i, i<64 — each group's 32 lanes read one block's 32
//          contiguous floats (128 B, coalesced). All 1024 threads busy.
// Stage 2: 64 threads tree-combine the 16 sub-partials per (batch, slot).
// Stage 3: 32 lanes compute per-(b,c) means (empty -> 0), shuffle-reduce,
//          write scalar / (B*C).
__global__ __launch_bounds__(1024) void cwce_final(const float* __restrict__ ws,
                                                   float* __restrict__ out) {
    __shared__ float sb[32][2 * CC + 1];   // +1 pad: conflict-free column reads
    const int t    = threadIdx.x;          // 1024 threads
    const int slot = t & 31;               // slot in [0,32)
    const int g    = t >> 5;               // group in [0,32)
    const int b    = g >> 4;               // batch 0/1
    const int sub  = g & 15;               // sub-group in [0,16)

    float a = 0.0f;
    for (int blk = b * (NBLK / 2) + sub; blk < (b + 1) * (NBLK / 2); blk += 16)
        a += ws[blk * 32 + slot];          // 64 coalesced 128-B group-reads
    sb[g][slot] = a;
    __syncthreads();

    if (t < 64) {                          // one wave: (bb, kk) per lane
        const int bb = t >> 5, kk = t & 31;
        float tot = 0.0f;
#pragma unroll
        for (int s = 0; s < 16; ++s) tot += sb[bb * 16 + s][kk];
        sb[bb * 16][kk] = tot;             // totals row per batch
    }
    __syncthreads();

    if (t < 64) {
        float v = 0.0f;
        if (t < BB * CC) {                 // lanes [0,32): segment (b,c)
            const int bb = t >> 4, c = t & 15;
            const float sum = sb[bb * 16][c];
            const float cnt = sb[bb * 16][CC + c];
            v = (cnt > 0.0f) ? (sum / cnt) : 0.0f;
        }
#pragma unroll
        for (int off = 32; off >= 1; off >>= 1) v += __shfl_down(v, off);
        if (t == 0) out[0] = v * (1.0f / (BB * CC));
    }
}

extern "C" void kernel_launch(void* const* d_in, const int* in_sizes, int n_in,
                              void* d_out, int out_size, void* d_ws, size_t ws_size,
                              hipStream_t stream) {
    const float* x = (const float*)d_in[0];
    const int*   y = (const int*)d_in[1];
    float*       out = (float*)d_out;
    float*       ws  = (float*)d_ws;     // 2048 * 32 floats = 256 KB used

    // total threads = B * NVOX / 4 = 524288 -> 2048 blocks of 256
    cwce_main<<<NBLK, 256, 0, stream>>>(x, y, ws);
    cwce_final<<<1, 1024, 0, stream>>>(ws, out);
}